// Round 13
// baseline (119.515 us; speedup 1.0000x reference)
//
#include <hip/hip_runtime.h>
#include <math.h>

#define M_   2049
#define B_   16
#define N_   1024
#define TAU_ 2.821e-5
#define PI_  3.14159265358979323846
#define TWO_PI_ 6.283185307179586476925286766559

#define GS_CH    16     // point-chunks per batch in the scatter spread (256 blocks)
#define CV_SPLIT 16     // mp-split for conv (512 blocks)
#define MPAD     2052   // padded m-stride for conv partials

// LDS swizzle for the conv h-window: pad 1 double per 4 so the FIR
// lane-stride-4 read (word stride 8 -> 16-way conflict raw) becomes word
// stride 10 -> 4-way aliasing (~free).  [R7: conflicts 6.4M->76K]
#define SW(i) ((i) + ((i) >> 2))

// NOTES:
//  R10: cooperative grid.sync() ~60us each at 512 blocks (sync-flag refetch
//       across non-coherent XCD L2s) — multi-kernel graph dispatch is cheaper.
//  R12: never drop a phase below ~1 block/CU (64-block fmm / 256-block conv
//       cost ~+20us vs R9).  Inline f32 fold in fmm is numerically proven.
//  R11: any per-tap guard must stride when len can exceed blockDim.

// ---------------------------------------------------------------------------
// Kernel 1:
//  blocks [0,256):   gsum scatter into LDS bins (4 lanes/point), plain store
//                    to gpart[ch] slice.
//  blocks [256,261): h — full-j Chebyshev recurrence per thread
//                    cos((j+1)t) = 2cos(t)cos(jt) - cos((j-1)t),
//                    writing hhalf DIRECTLY (no fold needed).
// ---------------------------------------------------------------------------
__global__ void spread_h_kernel(const float* __restrict__ x,
                                const float* __restrict__ s0, const float* __restrict__ a0,
                                const float* __restrict__ s1, const float* __restrict__ a1,
                                double* __restrict__ gpart, double* __restrict__ hhalf) {
    __shared__ double smem[M_ + 64];
    const int bx  = blockIdx.x;
    const int tid = threadIdx.x;

    if (bx < GS_CH * B_) {
        // ---- gsum scatter ----
        const int b  = bx >> 4;            // / GS_CH
        const int ch = bx & 15;
        for (int i = tid; i < M_; i += 256) smem[i] = 0.0;
        __syncthreads();
        const int pl  = tid >> 2;          // local point 0..63
        const int sub = tid & 3;           // quarter-window
        const double du      = TWO_PI_ / (double)M_;
        const double inv4tau = 1.0 / (4.0 * TAU_);
        const double u = (double)x[b * N_ + ch * (N_ / GS_CH) + pl] * (TWO_PI_ / 10.0);
        const int mc = (int)(u / du + 0.5);
        const int start = mc - 33 + sub * 17;      // 4x17 covers mc-33 .. mc+34
        for (int i = 0; i < 17; ++i) {
            int m = start + i;
            if (m >= 0 && m < M_) {
                double d = u - du * (double)m;
                double t = d * d * inv4tau;
                if (t < 88.0) atomicAdd(&smem[m], (double)__expf(-(float)t));
            }
        }
        __syncthreads();
        double* gp = gpart + ((size_t)ch * B_ + b) * M_;
        for (int i = tid; i < M_; i += 256) gp[i] = smem[i];
    } else {
        // ---- h: both channels, full j range, direct hhalf write ----
        const int dt = bx - GS_CH * B_;    // d-tile 0..4
        double* cf0 = smem;                // 1024 coeffs, channel 0
        double* cf1 = smem + 1024;         // 1024 coeffs, channel 1
        const double sA = 5.0 * (double)s0[0];
        const double sB = 5.0 * (double)s1[0];
        const double A0 = -(double)a0[0] * 4.0 * PI_;
        const double A1 =  (double)a1[0] * 4.0 * PI_;
        for (int j = tid + 1; j <= 1024; j += 256) {
            double k2   = (double)j * (double)j;
            double dec2 = (PI_ / TAU_) * exp(2.0 * TAU_ * k2);   // deconv^2
            double base = 2.0 * (10.0 / TWO_PI_) * dec2 / (double)M_;
            cf0[j - 1] = base * (A0 / (k2 + sA * sA));
            double den = k2 + sB * sB;
            cf1[j - 1] = base * (A1 / (den * den));
        }
        __syncthreads();
        const int d = dt * 256 + tid;
        if (d <= 1024) {
            const double w0base = (10.0 / TWO_PI_) * (PI_ / TAU_) / (double)M_;
            double acc0 = w0base * (A0 / (sA * sA));
            double acc1 = w0base * (A1 / ((sB * sB) * (sB * sB)));
            const double theta = TWO_PI_ * (double)d / (double)M_;
            const double twoc1 = 2.0 * cos(theta);
            double cm1 = 1.0;              // cos(0)
            double c   = cos(theta);       // cos(1*theta)
            #pragma unroll 4
            for (int j = 1; j <= 1024; ++j) {
                acc0 += cf0[j - 1] * c;
                acc1 += cf1[j - 1] * c;
                double cn = fma(twoc1, c, -cm1);
                cm1 = c; c = cn;
            }
            hhalf[d]        = acc0;
            hhalf[1025 + d] = acc1;
        }
    }
}

// ---------------------------------------------------------------------------
// Kernel 2: part[s][b][c][m] = sum over mp-chunk s of gsum[b][mp]*h_c[(m-mp)%M]
// Inline gsum fold (16 gpart slices -> LDS gsl at staging; replaces the gred
// dispatch); FIR register-sliding-window over the swizzled LDS h-window;
// R=4 consecutive m per lane, both channels; plain stores to part slice.
// ---------------------------------------------------------------------------
__global__ void conv_kernel(const double* __restrict__ gpart, const double* __restrict__ hhalf,
                            double* __restrict__ part) {
    __shared__ double w0s[1456];        // SW(1153) <= 1441
    __shared__ double w1s[1456];
    __shared__ double red[512];
    __shared__ double gsl[132];
    const int mt = blockIdx.x;          // 0 or 1
    const int s  = blockIdx.y;          // mp-chunk 0..15
    const int b  = blockIdx.z;
    const int m0  = mt * 1024;
    const int p0  = (s * M_) / CV_SPLIT;
    const int p1  = ((s + 1) * M_) / CV_SPLIT;
    const int len = p1 - p0;            // 128 or 129
    const int wcount = 1024 + len;
    int base = m0 - (p0 + len - 1);
    while (base < 0) base += M_;
    for (int i = threadIdx.x; i < wcount; i += 256) {
        int idx = base + i;
        while (idx >= M_) idx -= M_;
        int d = (idx > 1024) ? (M_ - idx) : idx;   // h even
        w0s[SW(i)] = hhalf[d];
        w1s[SW(i)] = hhalf[1025 + d];
    }
    // inline gsum fold for this chunk
    if (threadIdx.x < len) {
        const size_t sstride = (size_t)B_ * M_;
        const double* gp = gpart + (size_t)b * M_ + p0 + threadIdx.x;
        double acc = 0.0;
        #pragma unroll
        for (int k = 0; k < GS_CH; ++k) acc += gp[(size_t)k * sstride];
        gsl[threadIdx.x] = acc;
    }
    __syncthreads();

    int q = 4 * threadIdx.x + len - 1;
    double c0w0 = w0s[SW(q)],   c0w1 = w0s[SW(q+1)], c0w2 = w0s[SW(q+2)], c0w3 = w0s[SW(q+3)];
    double c1w0 = w1s[SW(q)],   c1w1 = w1s[SW(q+1)], c1w2 = w1s[SW(q+2)], c1w3 = w1s[SW(q+3)];
    double a00 = 0.0, a01 = 0.0, a02 = 0.0, a03 = 0.0;
    double a10 = 0.0, a11 = 0.0, a12 = 0.0, a13 = 0.0;
    #pragma unroll 4
    for (int t = 0; t < len; ++t) {
        double g = gsl[t];              // wave-uniform LDS broadcast
        a00 += g * c0w0; a01 += g * c0w1; a02 += g * c0w2; a03 += g * c0w3;
        a10 += g * c1w0; a11 += g * c1w1; a12 += g * c1w2; a13 += g * c1w3;
        c0w3 = c0w2; c0w2 = c0w1; c0w1 = c0w0;
        c1w3 = c1w2; c1w2 = c1w1; c1w1 = c1w0;
        --q;
        c0w0 = w0s[SW(q)]; c1w0 = w1s[SW(q)];
    }
    {
        double* pv = part + (((size_t)s * B_ + b) * 2) * MPAD + m0 + 4 * threadIdx.x;
        pv[0]        = a00; pv[1]        = a01; pv[2]        = a02; pv[3]        = a03;
        pv[MPAD + 0] = a10; pv[MPAD + 1] = a11; pv[MPAD + 2] = a12; pv[MPAD + 3] = a13;
    }
    if (mt == 1) {      // m = 2048 side-reduction (mt uniform per block)
        double t0 = 0.0, t1 = 0.0;
        for (int mp = threadIdx.x; mp < len; mp += 256) {   // strided (R11 lesson)
            double g = gsl[mp];
            int qq = 1023 + len - mp;
            t0 += g * w0s[SW(qq)];
            t1 += g * w1s[SW(qq)];
        }
        red[threadIdx.x]       = t0;
        red[256 + threadIdx.x] = t1;
        __syncthreads();
        for (int off = 128; off > 0; off >>= 1) {
            if (threadIdx.x < off) {
                red[threadIdx.x]       += red[threadIdx.x + off];
                red[256 + threadIdx.x] += red[256 + threadIdx.x + off];
            }
            __syncthreads();
        }
        if (threadIdx.x == 0) {
            double* pv = part + (((size_t)s * B_ + b) * 2) * MPAD;
            pv[2048]        = red[0];
            pv[MPAD + 2048] = red[256];
        }
    }
}

// ---------------------------------------------------------------------------
// Kernel 3: fmm with inline part-fold.  256 blocks (1/CU) = B x 16 chunks of
// 64 points.  Each block folds the 16 part slices (f64 accumulators) into an
// f32 LDS copy of conv[b] (proven: absmax unchanged in R12), then 16
// lanes/point sample the +-34-bin window from LDS.
// ---------------------------------------------------------------------------
__global__ void fmm_kernel(const float* __restrict__ x, const double* __restrict__ part,
                           float* __restrict__ out) {
    __shared__ float cf[2 * M_];
    const int b  = blockIdx.x >> 4;
    const int pc = blockIdx.x & 15;    // point-chunk of 64
    const int tid = threadIdx.x;
    const size_t sstride = (size_t)B_ * 2 * MPAD;
    for (int i = tid; i < 2 * M_; i += 256) {
        const int c = (i >= M_) ? 1 : 0;
        const int m = i - c * M_;
        const double* pp = part + ((size_t)b * 2 + c) * MPAD + m;
        double acc = 0.0;
        #pragma unroll
        for (int k = 0; k < CV_SPLIT; ++k)
            acc += pp[(size_t)k * sstride];
        cf[i] = (float)acc;
    }
    __syncthreads();

    const int sub = tid & 15;          // lane within point-group
    const int pl  = tid >> 4;          // point 0..15 within pass
    const double du      = TWO_PI_ / (double)M_;
    const double inv4tau = 1.0 / (4.0 * TAU_);
    #pragma unroll
    for (int pass = 0; pass < 4; ++pass) {
        const int pt = b * N_ + pc * 64 + pass * 16 + pl;
        const double u = (double)x[pt] * (TWO_PI_ / 10.0);
        int mc = (int)(u / du + 0.5);
        int lo = mc - 34; if (lo < 0) lo = 0;
        int hi = mc + 34; if (hi > M_ - 1) hi = M_ - 1;
        double a0v = 0.0, a1v = 0.0;
        for (int m = lo + sub; m <= hi; m += 16) {
            double d = u - du * (double)m;
            float g = __expf(-(float)(d * d * inv4tau));
            a0v += (double)(g * cf[m]);
            a1v += (double)(g * cf[M_ + m]);
        }
        a0v += __shfl_xor(a0v, 1); a1v += __shfl_xor(a1v, 1);
        a0v += __shfl_xor(a0v, 2); a1v += __shfl_xor(a1v, 2);
        a0v += __shfl_xor(a0v, 4); a1v += __shfl_xor(a1v, 4);
        a0v += __shfl_xor(a0v, 8); a1v += __shfl_xor(a1v, 8);
        if (sub == 0) {
            out[pt * 2 + 0] = (float)(a0v / (double)M_);
            out[pt * 2 + 1] = (float)(a1v / (double)M_);
        }
    }
}

// ---------------------------------------------------------------------------
extern "C" void kernel_launch(void* const* d_in, const int* in_sizes, int n_in,
                              void* d_out, int out_size, void* d_ws, size_t ws_size,
                              hipStream_t stream) {
    (void)in_sizes; (void)n_in; (void)out_size; (void)ws_size;
    const float* x  = (const float*)d_in[0];
    const float* s0 = (const float*)d_in[1];
    const float* a0 = (const float*)d_in[2];
    const float* s1 = (const float*)d_in[3];
    const float* a1 = (const float*)d_in[4];
    float* out = (float*)d_out;

    // Workspace layout (f64); every cell plainly overwritten each call (~12.6 MB).
    double* hhalf = (double*)d_ws;                            // 2*1025        = 2050
    double* part  = hhalf + 2 * 1025;                         // 16*B*2*MPAD   = 1050624
    double* gpart = part + (size_t)CV_SPLIT * B_ * 2 * MPAD;  // GS_CH*B*M     = 524544

    hipLaunchKernelGGL(spread_h_kernel, dim3(GS_CH * B_ + 5), dim3(256), 0,
                       stream, x, s0, a0, s1, a1, gpart, hhalf);
    hipLaunchKernelGGL(conv_kernel, dim3(2, CV_SPLIT, B_), dim3(256), 0, stream,
                       gpart, hhalf, part);
    hipLaunchKernelGGL(fmm_kernel, dim3(B_ * 16), dim3(256), 0, stream,
                       x, part, out);
}